// Round 2
// baseline (1954.663 us; speedup 1.0000x reference)
//
#include <hip/hip_runtime.h>
#include <hip/hip_bf16.h>
#include <math.h>

typedef unsigned short u16;
typedef unsigned int   u32;

#define DEV static __device__ __forceinline__

static constexpr int LL = 128, DD = 512, HH = 256, KK = 5, NN = 1024;

// workspace byte offsets
static constexpr size_t OFF_QP   = 0;        // 512 f32
static constexpr size_t OFF_U    = 4096;     // 512 f32
static constexpr size_t OFF_CC   = 8192;     // 1 f32
static constexpr size_t OFF_SC   = 12288;    // 1024 f32
static constexpr size_t OFF_WSC  = 16384;    // 5 f32
static constexpr size_t OFF_IDX  = 16640;    // 5 int
static constexpr size_t OFF_HG   = 20480;    // [2 dir][2 parity][5][256] f32 = 20480B
static constexpr size_t OFF_BAR0 = 40960;    // 129 ints (zeroed each launch)
static constexpr size_t OFF_BAR1 = 45056;    // 129 ints
static constexpr size_t OFF_PRE  = 49152;    // [2][128][5][1024] f32 = 5242880B
static constexpr size_t OFF_OUT0 = OFF_PRE  + (size_t)2*LL*5*1024*4;
static constexpr size_t OFF_OUT1 = OFF_OUT0 + (size_t)5*LL*DD*4;

DEV float sigf(float x){ return 1.0f/(1.0f + expf(-x)); }

DEV void gbar(int* slot, int nwg) {
  __syncthreads();
  if (threadIdx.x == 0) {
    __hip_atomic_fetch_add(slot, 1, __ATOMIC_ACQ_REL, __HIP_MEMORY_SCOPE_AGENT);
    while (__hip_atomic_load(slot, __ATOMIC_ACQUIRE, __HIP_MEMORY_SCOPE_AGENT) < nwg) {}
  }
  __syncthreads();
}

// ---------------- query projection: qp = Wq @ q + bq ----------------
__global__ void k_qproj(const float* __restrict__ Wq, const float* __restrict__ q,
                        const float* __restrict__ bq, float* __restrict__ qp) {
  __shared__ float qs[512];
  int tid = threadIdx.x;                 // 512 threads
  qs[tid] = q[tid];
  __syncthreads();
  const float* row = Wq + (size_t)tid * 512;
  float acc = 0.f;
  for (int j = 0; j < 512; j += 4) {
    float4 w = *(const float4*)(row + j);
    acc += w.x * qs[j] + w.y * qs[j+1] + w.z * qs[j+2] + w.w * qs[j+3];
  }
  qp[tid] = acc + bq[tid];
}

// ---------------- u = Wk^T @ qp ; cconst = bk . qp ----------------
__global__ void k_keyvec(const float* __restrict__ Wk, const float* __restrict__ bk,
                         const float* __restrict__ qp, float* __restrict__ u,
                         float* __restrict__ cconst) {
  __shared__ float qs[512];
  __shared__ float red[512];
  int tid = threadIdx.x;                 // 512 threads
  qs[tid] = qp[tid];
  __syncthreads();
  float acc = 0.f;
  for (int j = 0; j < 512; ++j) acc += Wk[(size_t)j*512 + tid] * qs[j];
  u[tid] = acc;
  red[tid] = bk[tid] * qs[tid];
  __syncthreads();
  for (int off = 256; off > 0; off >>= 1) { if (tid < off) red[tid] += red[tid+off]; __syncthreads(); }
  if (tid == 0) cconst[0] = red[0];
}

// ---------------- scores[n] = (1/L) sum_{l,d} ep[n,l,d]*u[d] + c ----------------
__global__ void k_scores(const float* __restrict__ ep, const float* __restrict__ u,
                         const float* __restrict__ cconst, float* __restrict__ scores) {
  __shared__ float red[256];
  int tid = threadIdx.x, n = blockIdx.x;
  // each thread's d-offset is constant across its strided chunks: (4*tid) mod 512
  int d0 = (tid * 4) & 511;
  float u0 = u[d0+0], u1 = u[d0+1], u2 = u[d0+2], u3 = u[d0+3];
  const float* base = ep + (size_t)n * (LL*DD);
  float acc = 0.f;
  for (int c = tid; c < (LL*DD)/4; c += 256) {
    float4 v = *(const float4*)(base + (size_t)c*4);
    acc += v.x*u0 + v.y*u1 + v.z*u2 + v.w*u3;
  }
  red[tid] = acc;
  __syncthreads();
  for (int off = 128; off > 0; off >>= 1) { if (tid < off) red[tid] += red[tid+off]; __syncthreads(); }
  if (tid == 0) scores[n] = red[0] * (1.0f/LL) + cconst[0];
}

// ---------------- top-5 + age weights ----------------
__global__ void k_topk(const float* __restrict__ scores, const float* __restrict__ ages,
                       int* __restrict__ idx5, float* __restrict__ wsc) {
  __shared__ float s0[NN];
  __shared__ float sv[NN];
  __shared__ int   si[NN];
  __shared__ int   chosen[KK];
  int tid = threadIdx.x;                 // 1024 threads
  s0[tid] = scores[tid];
  __syncthreads();
  for (int r = 0; r < KK; ++r) {
    float v = s0[tid];
    for (int m = 0; m < r; ++m) if (chosen[m] == tid) v = -3.4e38f;
    sv[tid] = v; si[tid] = tid;
    __syncthreads();
    for (int off = 512; off > 0; off >>= 1) {
      if (tid < off) {
        float a = sv[tid], b = sv[tid+off];
        int ia = si[tid], ib = si[tid+off];
        if (b > a || (b == a && ib < ia)) { sv[tid] = b; si[tid] = ib; }
      }
      __syncthreads();
    }
    if (tid == 0) {
      int w = si[0];
      chosen[r] = w;
      idx5[r] = w;
      wsc[r] = 1.0f / (1.0f + ages[w] * 0.01f);
    }
    __syncthreads();
  }
}

// ---------------- pre-projection: pre[dir][t][b][g] = x[b,t,:] . w_ih[g,:] + b_ih[g] + b_hh[g] ----------------
// layer0: x = ep[idx[b],t,:] * wsc[b]  (ep != nullptr);  layer1: x = x1[b,t,:] (f32)
__global__ void k_pre(const float* __restrict__ ep, const float* __restrict__ x1,
                      const int* __restrict__ idx5, const float* __restrict__ wsc,
                      const float* __restrict__ wihF, const float* __restrict__ wihB,
                      const float* __restrict__ bihF, const float* __restrict__ bhhF,
                      const float* __restrict__ bihB, const float* __restrict__ bhhB,
                      float* __restrict__ pre) {
  int t = blockIdx.x, rb = blockIdx.y, dir = blockIdx.z;
  int tid = threadIdx.x;                 // 256 threads
  __shared__ __align__(16) float xs[5*512];
  __shared__ __align__(16) float wt[256*36];  // 256 rows x 32 cols, pad 36 (16B-aligned rows)
  if (ep) {
    for (int f = tid; f < 5*512; f += 256) {
      int b = f >> 9, i = f & 511;
      xs[f] = ep[((size_t)idx5[b]*LL + t)*DD + i] * wsc[b];
    }
  } else {
    for (int f = tid; f < 5*512; f += 256) {
      int b = f >> 9, i = f & 511;
      xs[f] = x1[((size_t)b*LL + t)*DD + i];
    }
  }
  const float* wih = dir ? wihB : wihF;
  const float* bih = dir ? bihB : bihF;
  const float* bhh = dir ? bhhB : bhhF;
  int r0 = rb * 256;
  float acc[5] = {0,0,0,0,0};
  for (int it = 0; it < 16; ++it) {
    __syncthreads();
    // stage 256 rows x 32 cols of w_ih (float4 chunks, coalesced in 128B rows)
    for (int c = tid; c < 2048; c += 256) {
      int rr = c >> 3;
      int ii = (c & 7) * 4;
      *(float4*)&wt[rr*36 + ii] = *(const float4*)&wih[(size_t)(r0+rr)*512 + it*32 + ii];
    }
    __syncthreads();
    const float* wrow = &wt[(size_t)tid*36];
    const float* xb = &xs[it*32];
    for (int ii = 0; ii < 32; ii += 4) {
      float4 w = *(const float4*)(wrow + ii);
      #pragma unroll
      for (int b = 0; b < 5; ++b) {
        float4 xv = *(const float4*)&xb[b*512 + ii];
        acc[b] += w.x*xv.x + w.y*xv.y + w.z*xv.z + w.w*xv.w;
      }
    }
  }
  int grow = r0 + tid;
  float bias = bih[grow] + bhh[grow];
  size_t pbase = (((size_t)dir*LL + t)*5)*1024 + grow;
  #pragma unroll
  for (int b = 0; b < 5; ++b) pre[pbase + (size_t)b*1024] = acc[b] + bias;
}

// ---------------- persistent bidirectional LSTM layer ----------------
// grid = 8 WGs x 1024 thr. WG = (dir = blk>>2, unit-block q = blk&3, 64 units each).
// thread = (p = tid&127 -> rows p and p+128 of the 256-row slice, jq = tid>>7 -> 32-wide j chunk)
// w_hh slice held in VGPRs (fp32, 64 regs/thread). h exchanged via agent-scope atomics,
// parity double-buffered; one pre-zeroed barrier slot per step.
__global__ __launch_bounds__(1024) void k_lstm(
    const float* __restrict__ whhF, const float* __restrict__ whhB,
    const float* __restrict__ pre, float* __restrict__ out,
    float* __restrict__ hg, int* __restrict__ bar) {
  int wg  = blockIdx.x;
  int dir = wg >> 2;
  int q   = wg & 3;
  int ubase = q * 64;
  int tid = threadIdx.x;
  int p  = tid & 127;
  int jq = tid >> 7;                       // 0..7
  int jb = jq * 32;
  const float* whh = dir ? whhB : whhF;

  __shared__ __align__(16) float h_lds[5*256];
  __shared__ float part[256*5*9];          // [row][b][jq], pad 9 (conflict-free)
  __shared__ float c_s[5*64];

  int rA = p, rB = p + 128;
  int gA = (rA >> 6)*256 + ubase + (rA & 63);
  int gB = (rB >> 6)*256 + ubase + (rB & 63);
  float wA[32], wB[32];
  #pragma unroll
  for (int m4 = 0; m4 < 8; ++m4) {
    float4 a = *(const float4*)(whh + (size_t)gA*256 + jb + m4*4);
    wA[m4*4+0] = a.x; wA[m4*4+1] = a.y; wA[m4*4+2] = a.z; wA[m4*4+3] = a.w;
    float4 b4 = *(const float4*)(whh + (size_t)gB*256 + jb + m4*4);
    wB[m4*4+0] = b4.x; wB[m4*4+1] = b4.y; wB[m4*4+2] = b4.z; wB[m4*4+3] = b4.w;
  }
  for (int f = tid; f < 5*64; f += 1024) c_s[f] = 0.f;
  // zero own slice of parity-0 h buffer
  float* hg_dir = hg + (size_t)dir * 2 * 1280;
  if (tid < 320) {
    int b = tid >> 6, u = tid & 63;
    __hip_atomic_store(&hg_dir[0*1280 + b*256 + ubase + u], 0.f,
                       __ATOMIC_RELAXED, __HIP_MEMORY_SCOPE_AGENT);
  }
  gbar(bar + 0, 8);

  for (int s = 0; s < LL; ++s) {
    int t = dir ? (LL-1-s) : s;
    const float* hrd = hg_dir + (size_t)(s & 1) * 1280;
    float*       hwr = hg_dir + (size_t)((s + 1) & 1) * 1280;
    // (A) gather full h_prev into LDS
    for (int f = tid; f < 1280; f += 1024)
      h_lds[f] = __hip_atomic_load(&hrd[f], __ATOMIC_RELAXED, __HIP_MEMORY_SCOPE_AGENT);
    __syncthreads();
    // (B) partial dot-products: 2 rows x 32-j per thread, weights in registers
    float accA[5], accB[5];
    #pragma unroll
    for (int b = 0; b < 5; ++b) {
      const float4* h4 = (const float4*)&h_lds[b*256 + jb];
      float aA = 0.f, aB = 0.f;
      #pragma unroll
      for (int m4 = 0; m4 < 8; ++m4) {
        float4 hv = h4[m4];
        aA += wA[m4*4+0]*hv.x + wA[m4*4+1]*hv.y + wA[m4*4+2]*hv.z + wA[m4*4+3]*hv.w;
        aB += wB[m4*4+0]*hv.x + wB[m4*4+1]*hv.y + wB[m4*4+2]*hv.z + wB[m4*4+3]*hv.w;
      }
      accA[b] = aA; accB[b] = aB;
    }
    #pragma unroll
    for (int b = 0; b < 5; ++b) {
      part[(rA*5 + b)*9 + jq] = accA[b];
      part[(rB*5 + b)*9 + jq] = accB[b];
    }
    __syncthreads();
    // (C) finalize 64 units x 5 batch
    if (tid < 320) {
      int b = tid >> 6, u = tid & 63;
      const float* prep = pre + (((size_t)dir*LL + t)*5 + b)*1024 + ubase + u;
      float g[4];
      #pragma unroll
      for (int gate = 0; gate < 4; ++gate) {
        int r = gate*64 + u;
        float sum = prep[gate*256];
        #pragma unroll
        for (int m = 0; m < 8; ++m) sum += part[(r*5 + b)*9 + m];
        g[gate] = sum;
      }
      float ig = sigf(g[0]), fg = sigf(g[1]), cc = tanhf(g[2]), og = sigf(g[3]);
      float cn = fg * c_s[b*64 + u] + ig * cc;
      c_s[b*64 + u] = cn;
      float hv = og * tanhf(cn);
      out[((size_t)b*LL + t)*DD + dir*HH + ubase + u] = hv;
      __hip_atomic_store(&hwr[b*256 + ubase + u], hv,
                         __ATOMIC_RELAXED, __HIP_MEMORY_SCOPE_AGENT);
    }
    gbar(bar + 1 + s, 8);
  }
}

// ---------------- attention epilogue ----------------
__global__ void k_attn(const float* __restrict__ out1, const float* __restrict__ csb,
                       float* __restrict__ outp) {
  int b = blockIdx.x, tid = threadIdx.x;   // 5 blocks x 256 threads
  __shared__ float cs[512];
  __shared__ float att[128];
  __shared__ float red[256];
  __shared__ float smax, ssum;
  cs[tid] = csb[tid]; cs[tid+256] = csb[tid+256];
  __syncthreads();
  {
    int t = tid & 127, half = tid >> 7;
    const float* row = out1 + ((size_t)b*LL + t)*DD + half*256;
    const float* c2 = cs + half*256;
    float a = 0.f;
    for (int d = 0; d < 256; ++d) a += row[d] * c2[d];
    red[tid] = a;
  }
  __syncthreads();
  if (tid < 128) att[tid] = red[tid] + red[tid+128];
  __syncthreads();
  if (tid < 64) red[tid] = fmaxf(att[tid], att[tid+64]);
  __syncthreads();
  if (tid == 0) { float m = red[0]; for (int o = 1; o < 64; ++o) m = fmaxf(m, red[o]); smax = m; }
  __syncthreads();
  if (tid < 128) att[tid] = expf(att[tid] - smax);
  __syncthreads();
  if (tid < 64) red[tid] = att[tid] + att[tid+64];
  __syncthreads();
  if (tid == 0) { float s = 0.f; for (int o = 0; o < 64; ++o) s += red[o]; ssum = s; }
  __syncthreads();
  float inv = 1.0f / ssum;
  for (int d = tid; d < DD; d += 256) {
    float acc = 0.f;
    for (int t2 = 0; t2 < LL; ++t2) acc += att[t2] * out1[((size_t)b*LL + t2)*DD + d];
    outp[b*DD + d] = acc * inv;
  }
}

extern "C" void kernel_launch(void* const* d_in, const int* in_sizes, int n_in,
                              void* d_out, int out_size, void* d_ws, size_t ws_size,
                              hipStream_t stream) {
  (void)in_sizes; (void)n_in; (void)out_size; (void)ws_size;
  const float* ep   = (const float*)d_in[0];
  const float* qu   = (const float*)d_in[1];
  const float* cst  = (const float*)d_in[2];
  const float* ages = (const float*)d_in[3];
  const float* Wq   = (const float*)d_in[4];
  const float* bq   = (const float*)d_in[5];
  const float* Wk   = (const float*)d_in[6];
  const float* bk   = (const float*)d_in[7];
  const float *wih[4], *whh[4], *bih[4], *bhh[4];
  for (int l = 0; l < 4; ++l) {
    wih[l] = (const float*)d_in[8 + l*4 + 0];
    whh[l] = (const float*)d_in[8 + l*4 + 1];
    bih[l] = (const float*)d_in[8 + l*4 + 2];
    bhh[l] = (const float*)d_in[8 + l*4 + 3];
  }
  char* ws = (char*)d_ws;
  float* qp   = (float*)(ws + OFF_QP);
  float* uvec = (float*)(ws + OFF_U);
  float* cc   = (float*)(ws + OFF_CC);
  float* sc   = (float*)(ws + OFF_SC);
  float* wsc  = (float*)(ws + OFF_WSC);
  int*   idx5 = (int*)  (ws + OFF_IDX);
  float* hg   = (float*)(ws + OFF_HG);
  int*   bar0 = (int*)  (ws + OFF_BAR0);
  int*   bar1 = (int*)  (ws + OFF_BAR1);
  float* pre  = (float*)(ws + OFF_PRE);
  float* out0 = (float*)(ws + OFF_OUT0);
  float* out1 = (float*)(ws + OFF_OUT1);

  hipMemsetAsync(ws + OFF_BAR0, 0, 8192, stream);   // both barrier regions

  k_qproj <<<1, 512, 0, stream>>>(Wq, qu, bq, qp);
  k_keyvec<<<1, 512, 0, stream>>>(Wk, bk, qp, uvec, cc);
  k_scores<<<NN, 256, 0, stream>>>(ep, uvec, cc, sc);
  k_topk  <<<1, 1024, 0, stream>>>(sc, ages, idx5, wsc);

  k_pre <<<dim3(LL,4,2), 256, 0, stream>>>(ep, nullptr, idx5, wsc,
        wih[0], wih[1], bih[0], bhh[0], bih[1], bhh[1], pre);
  k_lstm<<<8, 1024, 0, stream>>>(whh[0], whh[1], pre, out0, hg, bar0);

  k_pre <<<dim3(LL,4,2), 256, 0, stream>>>(nullptr, out0, idx5, wsc,
        wih[2], wih[3], bih[2], bhh[2], bih[3], bhh[3], pre);
  k_lstm<<<8, 1024, 0, stream>>>(whh[2], whh[3], pre, out1, hg, bar1);

  k_attn<<<KK, 256, 0, stream>>>(out1, cst, (float*)d_out);
}

// Round 3
// 1553.418 us; speedup vs baseline: 1.2583x; 1.2583x over previous
//
#include <hip/hip_runtime.h>
#include <hip/hip_bf16.h>
#include <math.h>

typedef unsigned short u16;
typedef unsigned int   u32;

#define DEV static __device__ __forceinline__

static constexpr int LL = 128, DD = 512, HH = 256, KK = 5, NN = 1024;

// workspace byte offsets
static constexpr size_t OFF_QP   = 0;        // 512 f32
static constexpr size_t OFF_U    = 4096;     // 512 f32
static constexpr size_t OFF_CC   = 8192;     // 1 f32
static constexpr size_t OFF_SC   = 12288;    // 1024 f32
static constexpr size_t OFF_WSC  = 16384;    // 5 f32
static constexpr size_t OFF_IDX  = 16640;    // 5 int
static constexpr size_t OFF_HG   = 20480;    // [2 layers][2 dir][2 parity][5][256] f32 = 40960B
static constexpr size_t OFF_FLG0 = 61440;    // layer0 flags (4KB; dir stride 256B)
static constexpr size_t OFF_FLG1 = 65536;    // layer1 flags (4KB)
static constexpr size_t OFF_PRE  = 73728;    // [2][128][5][1024] f32 = 5242880B
static constexpr size_t OFF_OUT0 = OFF_PRE  + (size_t)2*LL*5*1024*4;
static constexpr size_t OFF_OUT1 = OFF_OUT0 + (size_t)5*LL*DD*4;

DEV float sigf(float x){ return 1.0f/(1.0f + expf(-x)); }

// ---------------- query projection: qp = Wq @ q + bq ----------------
__global__ void k_qproj(const float* __restrict__ Wq, const float* __restrict__ q,
                        const float* __restrict__ bq, float* __restrict__ qp) {
  __shared__ float qs[512];
  int tid = threadIdx.x;                 // 512 threads
  qs[tid] = q[tid];
  __syncthreads();
  const float* row = Wq + (size_t)tid * 512;
  float acc = 0.f;
  for (int j = 0; j < 512; j += 4) {
    float4 w = *(const float4*)(row + j);
    acc += w.x * qs[j] + w.y * qs[j+1] + w.z * qs[j+2] + w.w * qs[j+3];
  }
  qp[tid] = acc + bq[tid];
}

// ---------------- u = Wk^T @ qp ; cconst = bk . qp ----------------
__global__ void k_keyvec(const float* __restrict__ Wk, const float* __restrict__ bk,
                         const float* __restrict__ qp, float* __restrict__ u,
                         float* __restrict__ cconst) {
  __shared__ float qs[512];
  __shared__ float red[512];
  int tid = threadIdx.x;                 // 512 threads
  qs[tid] = qp[tid];
  __syncthreads();
  float acc = 0.f;
  for (int j = 0; j < 512; ++j) acc += Wk[(size_t)j*512 + tid] * qs[j];
  u[tid] = acc;
  red[tid] = bk[tid] * qs[tid];
  __syncthreads();
  for (int off = 256; off > 0; off >>= 1) { if (tid < off) red[tid] += red[tid+off]; __syncthreads(); }
  if (tid == 0) cconst[0] = red[0];
}

// ---------------- scores[n] = (1/L) sum_{l,d} ep[n,l,d]*u[d] + c ----------------
__global__ void k_scores(const float* __restrict__ ep, const float* __restrict__ u,
                         const float* __restrict__ cconst, float* __restrict__ scores) {
  __shared__ float red[256];
  int tid = threadIdx.x, n = blockIdx.x;
  int d0 = (tid * 4) & 511;
  float u0 = u[d0+0], u1 = u[d0+1], u2 = u[d0+2], u3 = u[d0+3];
  const float* base = ep + (size_t)n * (LL*DD);
  float acc = 0.f;
  for (int c = tid; c < (LL*DD)/4; c += 256) {
    float4 v = *(const float4*)(base + (size_t)c*4);
    acc += v.x*u0 + v.y*u1 + v.z*u2 + v.w*u3;
  }
  red[tid] = acc;
  __syncthreads();
  for (int off = 128; off > 0; off >>= 1) { if (tid < off) red[tid] += red[tid+off]; __syncthreads(); }
  if (tid == 0) scores[n] = red[0] * (1.0f/LL) + cconst[0];
}

// ---------------- top-5 + age weights ----------------
__global__ void k_topk(const float* __restrict__ scores, const float* __restrict__ ages,
                       int* __restrict__ idx5, float* __restrict__ wsc) {
  __shared__ float s0[NN];
  __shared__ float sv[NN];
  __shared__ int   si[NN];
  __shared__ int   chosen[KK];
  int tid = threadIdx.x;                 // 1024 threads
  s0[tid] = scores[tid];
  __syncthreads();
  for (int r = 0; r < KK; ++r) {
    float v = s0[tid];
    for (int m = 0; m < r; ++m) if (chosen[m] == tid) v = -3.4e38f;
    sv[tid] = v; si[tid] = tid;
    __syncthreads();
    for (int off = 512; off > 0; off >>= 1) {
      if (tid < off) {
        float a = sv[tid], b = sv[tid+off];
        int ia = si[tid], ib = si[tid+off];
        if (b > a || (b == a && ib < ia)) { sv[tid] = b; si[tid] = ib; }
      }
      __syncthreads();
    }
    if (tid == 0) {
      int w = si[0];
      chosen[r] = w;
      idx5[r] = w;
      wsc[r] = 1.0f / (1.0f + ages[w] * 0.01f);
    }
    __syncthreads();
  }
}

// ---------------- pre-projection: pre[dir][t][b][g] = x[b,t,:] . w_ih[g,:] + b_ih[g] + b_hh[g] ----------------
__global__ void k_pre(const float* __restrict__ ep, const float* __restrict__ x1,
                      const int* __restrict__ idx5, const float* __restrict__ wsc,
                      const float* __restrict__ wihF, const float* __restrict__ wihB,
                      const float* __restrict__ bihF, const float* __restrict__ bhhF,
                      const float* __restrict__ bihB, const float* __restrict__ bhhB,
                      float* __restrict__ pre) {
  int t = blockIdx.x, rb = blockIdx.y, dir = blockIdx.z;
  int tid = threadIdx.x;                 // 256 threads
  __shared__ __align__(16) float xs[5*512];
  __shared__ __align__(16) float wt[256*36];
  if (ep) {
    for (int f = tid; f < 5*512; f += 256) {
      int b = f >> 9, i = f & 511;
      xs[f] = ep[((size_t)idx5[b]*LL + t)*DD + i] * wsc[b];
    }
  } else {
    for (int f = tid; f < 5*512; f += 256) {
      int b = f >> 9, i = f & 511;
      xs[f] = x1[((size_t)b*LL + t)*DD + i];
    }
  }
  const float* wih = dir ? wihB : wihF;
  const float* bih = dir ? bihB : bihF;
  const float* bhh = dir ? bhhB : bhhF;
  int r0 = rb * 256;
  float acc[5] = {0,0,0,0,0};
  for (int it = 0; it < 16; ++it) {
    __syncthreads();
    for (int c = tid; c < 2048; c += 256) {
      int rr = c >> 3;
      int ii = (c & 7) * 4;
      *(float4*)&wt[rr*36 + ii] = *(const float4*)&wih[(size_t)(r0+rr)*512 + it*32 + ii];
    }
    __syncthreads();
    const float* wrow = &wt[(size_t)tid*36];
    const float* xb = &xs[it*32];
    for (int ii = 0; ii < 32; ii += 4) {
      float4 w = *(const float4*)(wrow + ii);
      #pragma unroll
      for (int b = 0; b < 5; ++b) {
        float4 xv = *(const float4*)&xb[b*512 + ii];
        acc[b] += w.x*xv.x + w.y*xv.y + w.z*xv.z + w.w*xv.w;
      }
    }
  }
  int grow = r0 + tid;
  float bias = bih[grow] + bhh[grow];
  size_t pbase = (((size_t)dir*LL + t)*5)*1024 + grow;
  #pragma unroll
  for (int b = 0; b < 5; ++b) pre[pbase + (size_t)b*1024] = acc[b] + bias;
}

// ---------------- persistent bidirectional LSTM layer ----------------
// grid = 16 WGs x 1024 thr. WG = (dir = blk>>3, unit-chunk q = blk&7, 32 units each).
// thread = (p = tid&127 -> local gate row, jq = tid>>7 -> 32-wide col chunk).
// w_hh slice in VGPRs (32 fp32/thread). Sync: per-direction flag-per-WG step
// counters (relaxed atomics; __syncthreads' vmcnt(0) drain before s_barrier
// gives release ordering). Own h chunk stays in LDS; peers gathered from IF.
__global__ __launch_bounds__(1024) void k_lstm(
    const float* __restrict__ whhF, const float* __restrict__ whhB,
    const float* __restrict__ pre, float* __restrict__ out,
    float* __restrict__ hg, int* __restrict__ flg) {
  int wg  = blockIdx.x;
  int dir = wg >> 3;
  int q   = wg & 7;                       // unit chunk: units [q*32, q*32+32)
  int tid = threadIdx.x;
  int p   = tid & 127;                    // local gate row (gate = p>>5, unit = p&31)
  int jq  = tid >> 7;                     // 0..7
  int jb  = jq * 32;
  const float* whh = dir ? whhB : whhF;

  __shared__ __align__(16) float h_lds[5*256];
  __shared__ float part[128*5*9];         // [row][b][jq] pad 9
  __shared__ float c_s[5*32];
  __shared__ float pre_lds[5*128];

  // weight fragment: global gate row gr, cols [jb, jb+32)
  int gr = (p >> 5) * 256 + q * 32 + (p & 31);
  float w[32];
  #pragma unroll
  for (int m4 = 0; m4 < 8; ++m4) {
    float4 a = *(const float4*)(whh + (size_t)gr*256 + jb + m4*4);
    w[m4*4+0] = a.x; w[m4*4+1] = a.y; w[m4*4+2] = a.z; w[m4*4+3] = a.w;
  }
  for (int f = tid; f < 1280; f += 1024) h_lds[f] = 0.f;
  if (tid < 160) c_s[tid] = 0.f;
  float* hg_dir = hg + (size_t)dir * 2 * 1280;
  int*  flg_dir = flg + dir * 64;         // 8 ints used, dirs 256B apart
  __syncthreads();

  for (int s = 0; s < LL; ++s) {
    int t = dir ? (LL-1-s) : s;
    // prefetch pre[t] for this step (hides under the flag wait)
    if (tid < 640) {
      int b = tid >> 7, r = tid & 127;
      int grow = (r >> 5)*256 + q*32 + (r & 31);
      pre_lds[tid] = pre[(((size_t)dir*LL + t)*5 + b)*1024 + grow];
    }
    if (s > 0) {
      const float* hrd = hg_dir + (size_t)(s & 1) * 1280;
      if (tid < 8) {
        while (__hip_atomic_load(&flg_dir[tid], __ATOMIC_RELAXED,
                                 __HIP_MEMORY_SCOPE_AGENT) < s) {}
      }
      __syncthreads();
      // gather 1120 peer h values (own 160 already in LDS)
      for (int f = tid; f < 1120; f += 1024) {
        int b = f / 224, w2 = f % 224;
        int c7 = w2 >> 5, u = w2 & 31;
        int pch = c7 + (c7 >= q);
        int idx = b*256 + pch*32 + u;
        h_lds[idx] = __hip_atomic_load(&hrd[idx], __ATOMIC_RELAXED,
                                       __HIP_MEMORY_SCOPE_AGENT);
      }
    }
    __syncthreads();
    // (B) one row x 32 cols x 5 batches, weights in registers
    float acc[5];
    #pragma unroll
    for (int b = 0; b < 5; ++b) {
      const float4* h4 = (const float4*)&h_lds[b*256 + jb];
      float a = 0.f;
      #pragma unroll
      for (int m4 = 0; m4 < 8; ++m4) {
        float4 hv = h4[m4];
        a += w[m4*4+0]*hv.x + w[m4*4+1]*hv.y + w[m4*4+2]*hv.z + w[m4*4+3]*hv.w;
      }
      acc[b] = a;
    }
    #pragma unroll
    for (int b = 0; b < 5; ++b) part[(p*5 + b)*9 + jq] = acc[b];
    __syncthreads();
    // (C) finalize 32 units x 5 batches
    if (tid < 160) {
      int b = tid >> 5, u = tid & 31;
      float g[4];
      #pragma unroll
      for (int gate = 0; gate < 4; ++gate) {
        int r = gate*32 + u;
        float sum = pre_lds[b*128 + r];
        #pragma unroll
        for (int m = 0; m < 8; ++m) sum += part[(r*5 + b)*9 + m];
        g[gate] = sum;
      }
      float ig = sigf(g[0]), fg = sigf(g[1]), cc = tanhf(g[2]), og = sigf(g[3]);
      float cn = fg * c_s[b*32 + u] + ig * cc;
      c_s[b*32 + u] = cn;
      float hv = og * tanhf(cn);
      out[((size_t)b*LL + t)*DD + dir*HH + q*32 + u] = hv;
      h_lds[b*256 + q*32 + u] = hv;      // own chunk for next step
      float* hwr = hg_dir + (size_t)((s + 1) & 1) * 1280;
      __hip_atomic_store(&hwr[b*256 + q*32 + u], hv,
                         __ATOMIC_RELAXED, __HIP_MEMORY_SCOPE_AGENT);
    }
    __syncthreads();   // vmcnt(0) drain before s_barrier => stores at IF
    if (tid == 0)
      __hip_atomic_store(&flg_dir[q], s + 1, __ATOMIC_RELAXED,
                         __HIP_MEMORY_SCOPE_AGENT);
  }
}

// ---------------- attention epilogue ----------------
__global__ void k_attn(const float* __restrict__ out1, const float* __restrict__ csb,
                       float* __restrict__ outp) {
  int b = blockIdx.x, tid = threadIdx.x;   // 5 blocks x 256 threads
  __shared__ float cs[512];
  __shared__ float att[128];
  __shared__ float red[256];
  __shared__ float smax, ssum;
  cs[tid] = csb[tid]; cs[tid+256] = csb[tid+256];
  __syncthreads();
  {
    int t = tid & 127, half = tid >> 7;
    const float* row = out1 + ((size_t)b*LL + t)*DD + half*256;
    const float* c2 = cs + half*256;
    float a = 0.f;
    for (int d = 0; d < 256; ++d) a += row[d] * c2[d];
    red[tid] = a;
  }
  __syncthreads();
  if (tid < 128) att[tid] = red[tid] + red[tid+128];
  __syncthreads();
  if (tid < 64) red[tid] = fmaxf(att[tid], att[tid+64]);
  __syncthreads();
  if (tid == 0) { float m = red[0]; for (int o = 1; o < 64; ++o) m = fmaxf(m, red[o]); smax = m; }
  __syncthreads();
  if (tid < 128) att[tid] = expf(att[tid] - smax);
  __syncthreads();
  if (tid < 64) red[tid] = att[tid] + att[tid+64];
  __syncthreads();
  if (tid == 0) { float s = 0.f; for (int o = 0; o < 64; ++o) s += red[o]; ssum = s; }
  __syncthreads();
  float inv = 1.0f / ssum;
  for (int d = tid; d < DD; d += 256) {
    float acc = 0.f;
    for (int t2 = 0; t2 < LL; ++t2) acc += att[t2] * out1[((size_t)b*LL + t2)*DD + d];
    outp[b*DD + d] = acc * inv;
  }
}

extern "C" void kernel_launch(void* const* d_in, const int* in_sizes, int n_in,
                              void* d_out, int out_size, void* d_ws, size_t ws_size,
                              hipStream_t stream) {
  (void)in_sizes; (void)n_in; (void)out_size; (void)ws_size;
  const float* ep   = (const float*)d_in[0];
  const float* qu   = (const float*)d_in[1];
  const float* cst  = (const float*)d_in[2];
  const float* ages = (const float*)d_in[3];
  const float* Wq   = (const float*)d_in[4];
  const float* bq   = (const float*)d_in[5];
  const float* Wk   = (const float*)d_in[6];
  const float* bk   = (const float*)d_in[7];
  const float *wih[4], *whh[4], *bih[4], *bhh[4];
  for (int l = 0; l < 4; ++l) {
    wih[l] = (const float*)d_in[8 + l*4 + 0];
    whh[l] = (const float*)d_in[8 + l*4 + 1];
    bih[l] = (const float*)d_in[8 + l*4 + 2];
    bhh[l] = (const float*)d_in[8 + l*4 + 3];
  }
  char* ws = (char*)d_ws;
  float* qp   = (float*)(ws + OFF_QP);
  float* uvec = (float*)(ws + OFF_U);
  float* cc   = (float*)(ws + OFF_CC);
  float* sc   = (float*)(ws + OFF_SC);
  float* wsc  = (float*)(ws + OFF_WSC);
  int*   idx5 = (int*)  (ws + OFF_IDX);
  float* hg0  = (float*)(ws + OFF_HG);
  float* hg1  = (float*)(ws + OFF_HG + 20480);
  int*   flg0 = (int*)  (ws + OFF_FLG0);
  int*   flg1 = (int*)  (ws + OFF_FLG1);
  float* pre  = (float*)(ws + OFF_PRE);
  float* out0 = (float*)(ws + OFF_OUT0);
  float* out1 = (float*)(ws + OFF_OUT1);

  hipMemsetAsync(ws + OFF_FLG0, 0, 8192, stream);   // both layers' flags

  k_qproj <<<1, 512, 0, stream>>>(Wq, qu, bq, qp);
  k_keyvec<<<1, 512, 0, stream>>>(Wk, bk, qp, uvec, cc);
  k_scores<<<NN, 256, 0, stream>>>(ep, uvec, cc, sc);
  k_topk  <<<1, 1024, 0, stream>>>(sc, ages, idx5, wsc);

  k_pre <<<dim3(LL,4,2), 256, 0, stream>>>(ep, nullptr, idx5, wsc,
        wih[0], wih[1], bih[0], bhh[0], bih[1], bhh[1], pre);
  k_lstm<<<16, 1024, 0, stream>>>(whh[0], whh[1], pre, out0, hg0, flg0);

  k_pre <<<dim3(LL,4,2), 256, 0, stream>>>(nullptr, out0, idx5, wsc,
        wih[2], wih[3], bih[2], bhh[2], bih[3], bhh[3], pre);
  k_lstm<<<16, 1024, 0, stream>>>(whh[2], whh[3], pre, out1, hg1, flg1);

  k_attn<<<KK, 256, 0, stream>>>(out1, cst, (float*)d_out);
}